// Round 1
// baseline (141.918 us; speedup 1.0000x reference)
//
#include <hip/hip_runtime.h>

#define N_ATOMS 1024
#define N_EDGES 8192
#define NBATCH  256
#define NEG     0.01f

typedef unsigned int u32;

// ---------- bf16 helpers (manual, RNE) ----------
__device__ __forceinline__ float bf_lo(u32 u) { return __uint_as_float(u << 16); }
__device__ __forceinline__ float bf_hi(u32 u) { return __uint_as_float(u & 0xffff0000u); }
__device__ __forceinline__ u32 bf_rne(float f) {
    u32 u = __float_as_uint(f);
    return (u + 0x7fffu + ((u >> 16) & 1u)) >> 16;
}
__device__ __forceinline__ u32 pack_bf(float lo, float hi) {
    return bf_rne(lo) | (bf_rne(hi) << 16);
}

// ---------- workspace layout ----------
#define ROWPTR_OFF 0            // int[1025]   (pad to 4352 B)
#define COLW_OFF   4352         // int2[8192]  = 65536 B
#define DINV_OFF   (4352 + 65536)          // float[1024]
#define SELFW_OFF  (4352 + 65536 + 4096)   // float[1024]

// ---------- LDS layout of main kernel ----------
#define TSTR 72                               // tile row stride in bf16 (144 B, 16B-aligned)
#define SM_TILE_BYTES (N_ATOMS * TSTR * 2)    // 147456
#define SM_CT_OFF SM_TILE_BYTES               // ctile: 1024*3 floats = 12288 B (aliased by pool)
#define SM_TOTAL (SM_TILE_BYTES + 12288)      // 159744 <= 163840

// =====================================================================
// Kernel 1: build CSR (grouped by dst) + normalization weights. 1 block.
// =====================================================================
__global__ __launch_bounds__(1024) void build_csr(
    const int* __restrict__ ei,          // [2, E]: row0 = src, row1 = dst
    int*  __restrict__ rowptr,           // [1025]
    int2* __restrict__ colw,             // [E]: {src, w_bits}
    float* __restrict__ dinv_g,          // [1024]
    float* __restrict__ selfw_g)         // [1024]
{
    __shared__ int   sdeg[N_ATOMS];
    __shared__ int   sscan[N_ATOMS];
    __shared__ int   sstart[N_ATOMS];
    __shared__ float sdinv[N_ATOMS];
    const int t = threadIdx.x;
    const int* srcA = ei;
    const int* dstA = ei + N_EDGES;

    sdeg[t] = 0;
    __syncthreads();
    #pragma unroll
    for (int e = t; e < N_EDGES; e += 1024) atomicAdd(&sdeg[dstA[e]], 1);
    __syncthreads();

    const int myv = sdeg[t];
    sscan[t] = myv;
    __syncthreads();
    // Hillis-Steele inclusive scan
    for (int off = 1; off < N_ATOMS; off <<= 1) {
        int add = 0;
        if (t >= off) add = sscan[t - off];
        __syncthreads();
        sscan[t] += add;
        __syncthreads();
    }
    const int start = sscan[t] - myv;
    sstart[t] = start;
    const float dv = rsqrtf((float)myv + 1.0f);
    sdinv[t] = dv;
    rowptr[t] = start;
    if (t == N_ATOMS - 1) rowptr[N_ATOMS] = sscan[N_ATOMS - 1];
    dinv_g[t]  = dv;
    selfw_g[t] = dv * dv;
    sdeg[t] = 0;   // reuse as fill counters
    __syncthreads();

    for (int e = t; e < N_EDGES; e += 1024) {
        const int d = dstA[e];
        const int s = srcA[e];
        const int slot = atomicAdd(&sdeg[d], 1);
        const float w = sdinv[s] * sdinv[d];
        colw[sstart[d] + slot] = make_int2(s, __float_as_int(w));
    }
}

// =====================================================================
// Kernel 2: fused GCN x2 + mean-pool + project. 1 block per molecule.
// 512 threads, 2 atoms/thread.
// =====================================================================
__global__ __launch_bounds__(512, 2) void gnn_main(
    const float* __restrict__ x,
    const int*  __restrict__ rowptr,
    const int2* __restrict__ colw,
    const float* __restrict__ selfw_g,
    const float* __restrict__ W1, const float* __restrict__ b1,
    const float* __restrict__ W2, const float* __restrict__ b2,
    const float* __restrict__ Wp, const float* __restrict__ bp,
    float* __restrict__ out)
{
    extern __shared__ char smem[];
    float* ctile = (float*)(smem + SM_CT_OFF);   // [1024*3] coords
    float* wpool = ctile;                        // aliased after ctile dead: [8][64]
    float* gvec  = ctile + 512;                  // [64]

    const int t = threadIdx.x;
    const int b = blockIdx.x;
    const float* xb = x + (size_t)b * (3 * N_ATOMS);

    // ---- phase 0: coords -> ctile (coalesced) ----
    #pragma unroll
    for (int i = 0; i < 6; ++i) ctile[t + i * 512] = xb[t + i * 512];
    __syncthreads();

    // ---- phase 1: aggregate coords (3 feats), GEMM1 + leaky -> bf16 tile ----
    #pragma unroll
    for (int a = 0; a < 2; ++a) {
        const int atom = t + a * 512;
        const int s0 = rowptr[atom], s1 = rowptr[atom + 1];
        float A0, A1, A2;
        {
            const float sw = selfw_g[atom];
            A0 = sw * ctile[atom * 3 + 0];
            A1 = sw * ctile[atom * 3 + 1];
            A2 = sw * ctile[atom * 3 + 2];
        }
        for (int j = s0; j < s1; ++j) {
            const int2 cw = colw[j];
            const float wt = __int_as_float(cw.y);
            const float* cr = ctile + cw.x * 3;
            A0 += wt * cr[0]; A1 += wt * cr[1]; A2 += wt * cr[2];
        }
        u32* trow = (u32*)(smem + (size_t)atom * (TSTR * 2));
        #pragma unroll
        for (int h = 0; h < 2; ++h) {
            float o[32];
            #pragma unroll
            for (int f = 0; f < 32; ++f) {
                const int fc = h * 32 + f;
                float v = b1[fc] + A0 * W1[fc] + A1 * W1[64 + fc] + A2 * W1[128 + fc];
                o[f] = fmaxf(v, NEG * v);   // leaky relu
            }
            #pragma unroll
            for (int p = 0; p < 16; ++p) trow[h * 16 + p] = pack_bf(o[2 * p], o[2 * p + 1]);
        }
    }
    __syncthreads();

    // ---- phase 2: aggregate h1 over edges (bf16 tile -> fp32 acc) ----
    float acc0[64], acc1[64];
    auto agg_row = [&](int atom, float (&acc)[64]) {
        #pragma unroll
        for (int f = 0; f < 64; ++f) acc[f] = 0.0f;
        const int s0 = rowptr[atom], s1 = rowptr[atom + 1];
        // iteration j = s0-1 is the self-loop term
        int   c  = atom;
        float wt = selfw_g[atom];
        for (int j = s0 - 1; j < s1; ++j) {
            const uint4* row = (const uint4*)(smem + (size_t)c * (TSTR * 2));
            const float wcur = wt;
            if (j + 1 < s1) {            // prefetch next edge
                const int2 cw = colw[j + 1];
                c = cw.x; wt = __int_as_float(cw.y);
            }
            #pragma unroll
            for (int m = 0; m < 8; ++m) {
                const uint4 q = row[m];
                acc[8*m+0] += wcur * bf_lo(q.x);
                acc[8*m+1] += wcur * bf_hi(q.x);
                acc[8*m+2] += wcur * bf_lo(q.y);
                acc[8*m+3] += wcur * bf_hi(q.y);
                acc[8*m+4] += wcur * bf_lo(q.z);
                acc[8*m+5] += wcur * bf_hi(q.z);
                acc[8*m+6] += wcur * bf_lo(q.w);
                acc[8*m+7] += wcur * bf_hi(q.w);
            }
        }
    };
    agg_row(t,       acc0);
    agg_row(t + 512, acc1);
    __syncthreads();

    // write aggregated h1 (bf16) back into tile
    {
        u32* trow0 = (u32*)(smem + (size_t)t * (TSTR * 2));
        u32* trow1 = (u32*)(smem + (size_t)(t + 512) * (TSTR * 2));
        #pragma unroll
        for (int p = 0; p < 32; ++p) trow0[p] = pack_bf(acc0[2 * p], acc0[2 * p + 1]);
        #pragma unroll
        for (int p = 0; p < 32; ++p) trow1[p] = pack_bf(acc1[2 * p], acc1[2 * p + 1]);
    }
    __syncthreads();

    // ---- phase 3: GEMM2 (W2 via SGPR scalar loads) + leaky + pool ----
    #pragma unroll
    for (int h = 0; h < 2; ++h) {
        float pl[32];
        #pragma unroll
        for (int f = 0; f < 32; ++f) pl[f] = 0.0f;
        #pragma unroll
        for (int a = 0; a < 2; ++a) {
            const int atom = t + a * 512;
            const uint4* row = (const uint4*)(smem + (size_t)atom * (TSTR * 2));
            float o[32];
            #pragma unroll
            for (int f = 0; f < 32; ++f) o[f] = b2[h * 32 + f];
            #pragma unroll
            for (int kc = 0; kc < 8; ++kc) {
                const uint4 q = row[kc];
                float av[8];
                av[0] = bf_lo(q.x); av[1] = bf_hi(q.x);
                av[2] = bf_lo(q.y); av[3] = bf_hi(q.y);
                av[4] = bf_lo(q.z); av[5] = bf_hi(q.z);
                av[6] = bf_lo(q.w); av[7] = bf_hi(q.w);
                #pragma unroll
                for (int j = 0; j < 8; ++j) {
                    const float* wrow = W2 + (kc * 8 + j) * 64 + h * 32;  // uniform -> s_load
                    #pragma unroll
                    for (int f = 0; f < 32; ++f) o[f] += av[j] * wrow[f];
                }
            }
            #pragma unroll
            for (int f = 0; f < 32; ++f) {
                float v = o[f];
                v = fmaxf(v, NEG * v);
                pl[f] += v;
            }
        }
        // wave butterfly reduce (64 lanes)
        #pragma unroll
        for (int f = 0; f < 32; ++f) {
            float v = pl[f];
            v += __shfl_xor(v, 1,  64);
            v += __shfl_xor(v, 2,  64);
            v += __shfl_xor(v, 4,  64);
            v += __shfl_xor(v, 8,  64);
            v += __shfl_xor(v, 16, 64);
            v += __shfl_xor(v, 32, 64);
            pl[f] = v;
        }
        if ((t & 63) == 0) {
            const int w = t >> 6;
            #pragma unroll
            for (int f = 0; f < 32; ++f) wpool[w * 64 + h * 32 + f] = pl[f];
        }
    }
    __syncthreads();

    if (t < 64) {
        float s = 0.0f;
        #pragma unroll
        for (int w = 0; w < 8; ++w) s += wpool[w * 64 + t];
        gvec[t] = s * (1.0f / 1024.0f);
    }
    __syncthreads();

    // ---- phase 4: project MLP (threads 0..127) ----
    if (t < 128) {
        float s = bp[t];
        #pragma unroll
        for (int f = 0; f < 64; ++f) s += gvec[f] * Wp[f * 128 + t];
        s = fmaxf(s, NEG * s);
        out[(size_t)b * 128 + t] = s;
    }
}

// =====================================================================
extern "C" void kernel_launch(void* const* d_in, const int* in_sizes, int n_in,
                              void* d_out, int out_size, void* d_ws, size_t ws_size,
                              hipStream_t stream) {
    const float* x  = (const float*)d_in[0];
    const int*   ei = (const int*)  d_in[1];
    const float* W1 = (const float*)d_in[2];
    const float* b1 = (const float*)d_in[3];
    const float* W2 = (const float*)d_in[4];
    const float* b2 = (const float*)d_in[5];
    const float* Wp = (const float*)d_in[6];
    const float* bp = (const float*)d_in[7];
    float* out = (float*)d_out;

    char* ws = (char*)d_ws;
    int*   rowptr = (int*)  (ws + ROWPTR_OFF);
    int2*  colw   = (int2*) (ws + COLW_OFF);
    float* dinv   = (float*)(ws + DINV_OFF);
    float* selfw  = (float*)(ws + SELFW_OFF);

    build_csr<<<1, 1024, 0, stream>>>(ei, rowptr, colw, dinv, selfw);

    (void)hipFuncSetAttribute((const void*)gnn_main,
                              hipFuncAttributeMaxDynamicSharedMemorySize, SM_TOTAL);
    gnn_main<<<NBATCH, 512, SM_TOTAL, stream>>>(
        x, rowptr, colw, selfw, W1, b1, W2, b2, Wp, bp, out);
}